// Round 4
// baseline (213.017 us; speedup 1.0000x reference)
//
#include <hip/hip_runtime.h>

using sh8 = __attribute__((ext_vector_type(8))) short;
using sh4 = __attribute__((ext_vector_type(4))) short;
using fx4 = __attribute__((ext_vector_type(4))) float;

#define MFMA(a,b,c)   __builtin_amdgcn_mfma_f32_16x16x32_bf16((a),(b),(c),0,0,0)

// RNE cast (epilogue scalars — accuracy-critical path)
__device__ __forceinline__ short f2bf(float f) {
    union { float f; unsigned u; } v; v.f = f;
    return (short)((v.u + 0x7fffu + ((v.u >> 16) & 1u)) >> 16);
}

// Single-instruction RNE pack of two floats to a bf16 pair (lo in low half).
__device__ __forceinline__ unsigned cvtpk(float lo, float hi) {
    unsigned r;
    asm("v_cvt_pk_bf16_f32 %0, %1, %2" : "=v"(r) : "v"(lo), "v"(hi));
    return r;
}

__device__ __forceinline__ sh8 pack8(float4 a, float4 b) {
    union { unsigned u[4]; sh8 s; } r;
    r.u[0] = cvtpk(a.x, a.y);
    r.u[1] = cvtpk(a.z, a.w);
    r.u[2] = cvtpk(b.x, b.y);
    r.u[3] = cvtpk(b.z, b.w);
    return r.s;
}

// q scale: D^-0.5 * log2(e) folded together; attn uses exp2 directly.
#define QSCALE 0.18033688011112042f

// DMA one 1KB chunk: per-lane global src, wave-uniform LDS dst (+lane*16 by HW)
#define GLOAD_LDS16(gsrc, ldst) __builtin_amdgcn_global_load_lds( \
    (const __attribute__((address_space(1))) void*)(gsrc),        \
    (__attribute__((address_space(3))) void*)(ldst), 16, 0, 0)

// ===========================================================================
// Fragment layouts (written by prep_k, consumed by attn_k):
//   k_ws : per bh, 256 chunks of 512 shorts. chunk fo = (kb*4+nt)*2+half
//          holds K[key=kb*64+nt*16+llo][d=half*32+lhi*8+j] at lane=lhi*16+llo,
//          slot j.  64-key block kb -> 8 consecutive chunks at fo = kb*8.
//   vT_ws: per bh, 256 chunks of 512 shorts. chunk vo = (kb*2+g)*4+dt holds
//          V[key=kb*64+g*32+(i>>2)*16+lhi*4+(i&3)][d=dt*16+llo] at
//          lane=lhi*16+llo, slot i.  64-key block kb -> 8 chunks at kb*8.
//   Chunks are lane-linear (lane*16B) => global_load_lds-compatible.
// ===========================================================================

// prep_k: merged qgemm+kvgemm (blocks 0..511, XCD-co-resident swizzle:
// each XCD owns 8 m-tiles x 8 n-tiles (6 q + 2 kv) so the x row-panel is
// fetched into that XCD's L2 once) + depth_k cast (512..1535) + depth_v
// fragment gather (1536..2047).
__global__ __launch_bounds__(256) void prep_k(const float* __restrict__ x,
                                              const float* __restrict__ Wq,
                                              const float* __restrict__ bq,
                                              const float* __restrict__ Wkv,
                                              const float* __restrict__ bkv,
                                              const float* __restrict__ dk,
                                              const float* __restrict__ dv,
                                              float* __restrict__ ok,
                                              float* __restrict__ ov,
                                              short* __restrict__ q_ws,
                                              short* __restrict__ k_ws,
                                              short* __restrict__ vT_ws)
{
    __shared__ alignas(16) short Al[128 * 40];
    __shared__ alignas(16) short Bl[128 * 40];
    const int blk = blockIdx.x;
    const int t   = threadIdx.x;

    if (blk < 512) {
        // ----- 128x128-tile bf16 GEMM path (qgemm or kvgemm) -----
        // XCD-co-residency swizzle: XCD x8 = blk&7 gets m-tiles [8*x8, 8*x8+8),
        // all 8 n-tiles of one m-tile co-resident (same-L2 sharing of A rows).
        const int x8 = blk & 7, jj = blk >> 3;       // jj in [0,64)
        const int m  = x8 * 8 + (jj >> 3);           // [0,64)
        const int nn = jj & 7;                       // [0,8): 0..5 q, 6..7 kv
        const bool isq = (nn < 6);
        const int  bm  = m * 128, bn = (isq ? nn : nn - 6) * 128;
        const float* Wmat = isq ? Wq : Wkv;

        const int wave = t >> 6, lane = t & 63;
        const int wm   = wave >> 1, wn = wave & 1;
        const int lhi  = lane >> 4, llo = lane & 15;

        const int srow = t >> 1, scol = (t & 1) * 16;
        const float* ap = x    + (size_t)(bm + srow) * 768 + scol;
        const float* bp = Wmat + (size_t)(bn + srow) * 768 + scol;

        fx4 zero = {0.f, 0.f, 0.f, 0.f};
        fx4 acc[4][4];
        #pragma unroll
        for (int a = 0; a < 4; ++a)
            #pragma unroll
            for (int b2 = 0; b2 < 4; ++b2) acc[a][b2] = zero;

        float4 pa0 = *(const float4*)(ap);     float4 pa1 = *(const float4*)(ap + 4);
        float4 pa2 = *(const float4*)(ap + 8); float4 pa3 = *(const float4*)(ap + 12);
        float4 pb0 = *(const float4*)(bp);     float4 pb1 = *(const float4*)(bp + 4);
        float4 pb2 = *(const float4*)(bp + 8); float4 pb3 = *(const float4*)(bp + 12);

        for (int k0 = 0; k0 < 768; k0 += 32) {
            __syncthreads();
            *(sh8*)&Al[srow*40 + scol]     = pack8(pa0, pa1);
            *(sh8*)&Al[srow*40 + scol + 8] = pack8(pa2, pa3);
            *(sh8*)&Bl[srow*40 + scol]     = pack8(pb0, pb1);
            *(sh8*)&Bl[srow*40 + scol + 8] = pack8(pb2, pb3);
            __syncthreads();
            if (k0 + 32 < 768) {
                pa0 = *(const float4*)(ap + k0+32);  pa1 = *(const float4*)(ap + k0+36);
                pa2 = *(const float4*)(ap + k0+40);  pa3 = *(const float4*)(ap + k0+44);
                pb0 = *(const float4*)(bp + k0+32);  pb1 = *(const float4*)(bp + k0+36);
                pb2 = *(const float4*)(bp + k0+40);  pb3 = *(const float4*)(bp + k0+44);
            }
            sh8 af[4], bf[4];
            #pragma unroll
            for (int mt = 0; mt < 4; ++mt)
                af[mt] = *(const sh8*)&Al[(wm*64 + mt*16 + llo)*40 + lhi*8];
            #pragma unroll
            for (int nt = 0; nt < 4; ++nt)
                bf[nt] = *(const sh8*)&Bl[(wn*64 + nt*16 + llo)*40 + lhi*8];
            #pragma unroll
            for (int mt = 0; mt < 4; ++mt)
                #pragma unroll
                for (int nt = 0; nt < 4; ++nt)
                    acc[mt][nt] = MFMA(af[mt], bf[nt], acc[mt][nt]);
        }

        if (isq) {
            #pragma unroll
            for (int nt = 0; nt < 4; ++nt) {
                const int c = bn + wn*64 + nt*16 + llo;
                const float bias = bq[c];
                const int g = c >> 7, h = (c >> 6) & 1, d = c & 63;
                #pragma unroll
                for (int mt = 0; mt < 4; ++mt) {
                    const int m0 = bm + wm*64 + mt*16 + lhi*4;
                    #pragma unroll
                    for (int r = 0; r < 4; ++r) {
                        const int mr = m0 + r;
                        const int b = mr >> 10, n = mr & 1023;
                        const float val = (acc[mt][nt][r] + bias) * QSCALE;
                        q_ws[((size_t)(b*2 + h)*6144 + n*6 + g)*64 + d] = f2bf(val);
                    }
                }
            }
        } else {
            #pragma unroll
            for (int nt = 0; nt < 4; ++nt) {
                const int c = bn + wn*64 + nt*16 + llo;     // 0..255
                const float bias = bkv[c];
                const int s = c >> 7, h = (c >> 6) & 1, d = c & 63;
                #pragma unroll
                for (int mt = 0; mt < 4; ++mt) {
                    const int m0 = bm + wm*64 + mt*16 + lhi*4;
                    const int b = m0 >> 10, n0 = m0 & 1023;
                    float vals[4];
                    #pragma unroll
                    for (int r = 0; r < 4; ++r) vals[r] = acc[mt][nt][r] + bias;
                    const int key = 1024 + n0;              // n0 % 4 == 0
                    if (s == 0) {
                        #pragma unroll
                        for (int r = 0; r < 4; ++r)
                            ok[((size_t)(b*1024 + n0 + r)*2 + h)*64 + d] = vals[r];
                        const int kb_ = key >> 6, nt_ = (key >> 4) & 3;
                        const int half = d >> 5, lhiK = (d >> 3) & 3, jK = d & 7;
                        const size_t base = (size_t)(b*2 + h)*131072
                            + (size_t)(((((kb_*4 + nt_)*2 + half)*64) + lhiK*16 + (key & 15))*8 + jK);
                        #pragma unroll
                        for (int r = 0; r < 4; ++r)
                            k_ws[base + r*8] = f2bf(vals[r]);
                    } else {
                        #pragma unroll
                        for (int r = 0; r < 4; ++r)
                            ov[((size_t)(b*1024 + n0 + r)*2 + h)*64 + d] = vals[r];
                        const int kb_ = key >> 6, g_ = (key >> 5) & 1, k5 = key & 31;
                        const int half5 = k5 >> 4, lhi5 = (k5 >> 2) & 3;   // j5 = r
                        const int dt_ = d >> 4, llov = d & 15;
                        short4 pk = make_short4(f2bf(vals[0]), f2bf(vals[1]),
                                                f2bf(vals[2]), f2bf(vals[3]));
                        const size_t base = (size_t)(b*2 + h)*131072
                            + (size_t)(((((kb_*2 + g_)*4 + dt_)*64) + lhi5*16 + llov)*8 + half5*4);
                        *(short4*)&vT_ws[base] = pk;
                    }
                }
            }
        }
    } else if (blk < 1536) {
        // ----- depth_k cast: [b][tt][h][d] fp32 -> k_ws fragment layout -----
        const size_t idx4 = ((size_t)(blk - 512) * 256 + t) * 4;
        const int b  = (int)(idx4 >> 17);
        const int rm = (int)(idx4 & 131071);
        const int tt = rm >> 7, h = (rm >> 6) & 1, d = rm & 63;   // d % 4 == 0
        float4 v = *(const float4*)(dk + idx4);
        short4 pk = make_short4(f2bf(v.x), f2bf(v.y), f2bf(v.z), f2bf(v.w));
        const int kb_ = tt >> 6, nt_ = (tt >> 4) & 3, lloK = tt & 15;
        const int half = d >> 5, lhiK = (d >> 3) & 3, jK = d & 7;  // jK in {0,4}
        const size_t addr = (size_t)(b*2 + h)*131072
            + (size_t)(((((kb_*4 + nt_)*2 + half)*64) + lhiK*16 + lloK)*8 + jK);
        *(short4*)&k_ws[addr] = pk;
    } else {
        // ----- depth_v: direct gather into V fragment layout -----
        const int unit = (blk - 1536)*4 + (t >> 6);   // 0..2047
        const int lane = t & 63, lhi = lane >> 4, llo = lane & 15;
        const int dt_ = unit & 3, g_ = (unit >> 2) & 1;
        const int kb_ = (unit >> 3) & 15, bh = unit >> 7;
        const int b = bh >> 1, h = bh & 1;
        const float* s0 = dv
            + ((size_t)((b*1024 + kb_*64 + g_*32 + lhi*4)*2 + h))*64 + dt_*16 + llo;
        union { short s[8]; sh8 v8; } o;
        #pragma unroll
        for (int jj = 0; jj < 4; ++jj) o.s[jj]     = f2bf(s0[(size_t)jj * 128]);
        #pragma unroll
        for (int jj = 0; jj < 4; ++jj) o.s[4 + jj] = f2bf(s0[(size_t)(16 + jj) * 128]);
        *(sh8*)&vT_ws[((size_t)bh*256 + (kb_*2 + g_)*4 + dt_)*512 + lane*8] = o.v8;
    }
}

// ---------------------------------------------------------------------------
// Attention v9: 64-key groups (32 iterations, ONE barrier per group), ring-2
// LDS double-buffer.  T3-minimal schedule: stage(next) issued right after the
// barrier (WAR-safe: barrier proves all waves finished reading that buffer),
// landing hidden under the current group's compute; one vmcnt(0)+s_barrier
// per group.  bh-co-location swizzle: XCD x8 gets bh {2*x8, 2*x8+1} so K/V
// working set (1 MB) lives in that XCD's L2.
// ---------------------------------------------------------------------------
__global__ __launch_bounds__(256) void attn_k(const short* __restrict__ q_ws,
                                              const short* __restrict__ k_ws,
                                              const short* __restrict__ vT_ws,
                                              short* __restrict__ o_ws)
{
    __shared__ alignas(16) short L[2][16][512];   // 32 KB: [buf][chunk][512]
    const int t    = threadIdx.x;
    const int wave = t >> 6, lane = t & 63;
    const int lhi  = lane >> 4, llo = lane & 15;
    const int blk  = blockIdx.x;
    const int x8   = blk & 7, jj = blk >> 3;       // jj in [0,96)
    const int bh   = x8 * 2 + (jj >= 48 ? 1 : 0);
    const int qt   = (jj >= 48) ? (jj - 48) : jj;  // [0,48)
    const int b    = bh >> 1, h = bh & 1;

    const short* qb = q_ws + ((size_t)bh*6144 + qt*128 + wave*32) * 64;
    sh8 qf[2][2];
    #pragma unroll
    for (int s = 0; s < 2; ++s) {
        qf[s][0] = *(const sh8*)(qb + (s*16 + llo)*64 + lhi*8);
        qf[s][1] = *(const sh8*)(qb + (s*16 + llo)*64 + lhi*8 + 32);
    }

    // wave stages chunks {2*wave, 2*wave+1} of K and of V for each group.
    const short* kbase = k_ws  + (size_t)bh*131072 + (wave*2)*512 + lane*8;
    const short* vbase = vT_ws + (size_t)bh*131072 + (wave*2)*512 + lane*8;

    auto stage = [&](int g) {
        const short* ks = kbase + (size_t)g * 4096;
        const short* vs = vbase + (size_t)g * 4096;
        GLOAD_LDS16(ks,       &L[g & 1][wave*2][0]);
        GLOAD_LDS16(ks + 512, &L[g & 1][wave*2 + 1][0]);
        GLOAD_LDS16(vs,       &L[g & 1][8 + wave*2][0]);
        GLOAD_LDS16(vs + 512, &L[g & 1][8 + wave*2 + 1][0]);
    };

    fx4 zero = {0.f, 0.f, 0.f, 0.f};
    fx4 oacc[2][4];
    fx4 lacc[2];
    #pragma unroll
    for (int s = 0; s < 2; ++s) {
        lacc[s] = zero;
        #pragma unroll
        for (int dt = 0; dt < 4; ++dt) oacc[s][dt] = zero;
    }

    union { unsigned u[4]; sh8 s8; } onesu;
    onesu.u[0] = onesu.u[1] = onesu.u[2] = onesu.u[3] = 0x3F803F80u;  // bf16 1.0 x8
    const sh8 ones = onesu.s8;

    stage(0);
    asm volatile("s_waitcnt vmcnt(0)" ::: "memory");
    __builtin_amdgcn_s_barrier();
    __builtin_amdgcn_sched_barrier(0);

    for (int g = 0; g < 32; ++g) {
        if (g < 31) stage(g + 1);   // lands in other buffer during this compute

        const short* Lb = (const short*)&L[g & 1][0][0];
        const int lo = lane * 8;

        // --- QK^T: 4 key-subtiles x 2 q-subtiles ---
        fx4 st[2][4];
        #pragma unroll
        for (int n = 0; n < 4; ++n) {
            sh8 k0 = *(const sh8*)(Lb + (n*2)*512 + lo);
            sh8 k1 = *(const sh8*)(Lb + (n*2 + 1)*512 + lo);
            st[0][n] = MFMA(k0, qf[0][0], zero);
            st[0][n] = MFMA(k1, qf[0][1], st[0][n]);
            st[1][n] = MFMA(k0, qf[1][0], zero);
            st[1][n] = MFMA(k1, qf[1][1], st[1][n]);
        }

        // --- softmax numerators: exp2 + pack to bf16 P fragments ---
        union { unsigned u[4]; sh8 s8; } pu[2][2];
        #pragma unroll
        for (int s = 0; s < 2; ++s)
            #pragma unroll
            for (int uu = 0; uu < 2; ++uu) {
                fx4 sa = st[s][uu*2], sb = st[s][uu*2 + 1];
                float a0 = __builtin_amdgcn_exp2f(sa[0]);
                float a1 = __builtin_amdgcn_exp2f(sa[1]);
                float a2 = __builtin_amdgcn_exp2f(sa[2]);
                float a3 = __builtin_amdgcn_exp2f(sa[3]);
                float b0 = __builtin_amdgcn_exp2f(sb[0]);
                float b1 = __builtin_amdgcn_exp2f(sb[1]);
                float b2 = __builtin_amdgcn_exp2f(sb[2]);
                float b3 = __builtin_amdgcn_exp2f(sb[3]);
                pu[s][uu].u[0] = cvtpk(a0, a1);
                pu[s][uu].u[1] = cvtpk(a2, a3);
                pu[s][uu].u[2] = cvtpk(b0, b1);
                pu[s][uu].u[3] = cvtpk(b2, b3);
            }

        // --- PV + ones-MFMA row sums ---
        #pragma unroll
        for (int uu = 0; uu < 2; ++uu) {
            sh8 v0 = *(const sh8*)(Lb + (8 + uu*4 + 0)*512 + lo);
            sh8 v1 = *(const sh8*)(Lb + (8 + uu*4 + 1)*512 + lo);
            sh8 v2 = *(const sh8*)(Lb + (8 + uu*4 + 2)*512 + lo);
            sh8 v3 = *(const sh8*)(Lb + (8 + uu*4 + 3)*512 + lo);
            #pragma unroll
            for (int s = 0; s < 2; ++s) {
                lacc[s]    = MFMA(pu[s][uu].s8, ones, lacc[s]);
                oacc[s][0] = MFMA(pu[s][uu].s8, v0, oacc[s][0]);
                oacc[s][1] = MFMA(pu[s][uu].s8, v1, oacc[s][1]);
                oacc[s][2] = MFMA(pu[s][uu].s8, v2, oacc[s][2]);
                oacc[s][3] = MFMA(pu[s][uu].s8, v3, oacc[s][3]);
            }
        }

        asm volatile("s_waitcnt vmcnt(0)" ::: "memory");   // next group landed
        __builtin_amdgcn_s_barrier();
        __builtin_amdgcn_sched_barrier(0);
    }

    // epilogue: lacc[s][r] already holds the full denominator for q-row
    // s*16 + lhi*4 + r (identical across llo) — no shuffles needed.
    #pragma unroll
    for (int s = 0; s < 2; ++s) {
        #pragma unroll
        for (int r = 0; r < 4; ++r) {
            const float iq = 1.0f / lacc[s][r];
            const int qi = qt*128 + wave*32 + s*16 + lhi*4 + r;
            const int n = qi / 6, g = qi % 6;
            short* orow = o_ws + ((size_t)(b*1024 + n))*768 + g*128 + h*64;
            #pragma unroll
            for (int dt = 0; dt < 4; ++dt)
                orow[dt*16 + llo] = f2bf(oacc[s][dt][r] * iq);
        }
    }
}

// ---------------------------------------------------------------------------
// proj GEMM: out = o(8192x768,bf16) @ Wproj^T + bproj -> fp32.
// 128x64 tiles, 768 blocks = 3/CU balanced.  XCD-co-residency swizzle:
// XCD x8 owns m-tiles [8*x8, 8*x8+8) with all 12 n-tiles co-resident, so the
// o_ws A-panel (1.6 MB bf16) is fetched into that XCD's L2 once.
// ---------------------------------------------------------------------------
__global__ __launch_bounds__(256) void projgemm_k(const short* __restrict__ o_ws,
                                                  const float* __restrict__ Wp,
                                                  const float* __restrict__ bpj,
                                                  float* __restrict__ out)
{
    __shared__ alignas(16) short Al[128 * 40];
    __shared__ alignas(16) short Bl[64 * 40];
    const int t    = threadIdx.x;
    const int wave = t >> 6, lane = t & 63;
    const int wm   = wave >> 1, wn = wave & 1;
    const int lhi  = lane >> 4, llo = lane & 15;
    const int x8   = blockIdx.x & 7, jj = blockIdx.x >> 3;   // jj in [0,96)
    const int bm   = (x8*8 + jj/12) * 128;
    const int bn   = (jj % 12) * 64;

    const int srow = t >> 1, scol = (t & 1) * 16;       // A stage: 128 rows x 32
    const int brow = t >> 2, bcol = (t & 3) * 8;        // B stage: 64 rows x 32
    const short* ap = o_ws + (size_t)(bm + srow) * 768 + scol;
    const float* bp = Wp   + (size_t)(bn + brow) * 768 + bcol;

    fx4 zero = {0.f, 0.f, 0.f, 0.f};
    fx4 acc[4][2];
    #pragma unroll
    for (int i = 0; i < 4; ++i)
        #pragma unroll
        for (int j2 = 0; j2 < 2; ++j2) acc[i][j2] = zero;

    sh8 qa0 = *(const sh8*)(ap), qa1 = *(const sh8*)(ap + 8);
    float4 pb0 = *(const float4*)(bp), pb1 = *(const float4*)(bp + 4);

    for (int k0 = 0; k0 < 768; k0 += 32) {
        __syncthreads();
        *(sh8*)&Al[srow*40 + scol] = qa0;
        *(sh8*)&Al[srow*40 + scol + 8] = qa1;
        *(sh8*)&Bl[brow*40 + bcol] = pack8(pb0, pb1);
        __syncthreads();
        if (k0 + 32 < 768) {
            qa0 = *(const sh8*)(ap + k0+32);  qa1 = *(const sh8*)(ap + k0+40);
            pb0 = *(const float4*)(bp + k0+32);  pb1 = *(const float4*)(bp + k0+36);
        }
        sh8 af[4], bf[2];
        #pragma unroll
        for (int mt = 0; mt < 4; ++mt)
            af[mt] = *(const sh8*)&Al[(wm*64 + mt*16 + llo)*40 + lhi*8];
        #pragma unroll
        for (int nt = 0; nt < 2; ++nt)
            bf[nt] = *(const sh8*)&Bl[(wn*32 + nt*16 + llo)*40 + lhi*8];
        #pragma unroll
        for (int mt = 0; mt < 4; ++mt)
            #pragma unroll
            for (int nt = 0; nt < 2; ++nt)
                acc[mt][nt] = MFMA(af[mt], bf[nt], acc[mt][nt]);
    }

    #pragma unroll
    for (int nt = 0; nt < 2; ++nt) {
        const int c = bn + wn*32 + nt*16 + llo;
        const float bias = bpj[c];
        #pragma unroll
        for (int mt = 0; mt < 4; ++mt) {
            const int m0 = bm + wm*64 + mt*16 + lhi*4;
            #pragma unroll
            for (int r = 0; r < 4; ++r)
                out[(size_t)(m0 + r)*768 + c] = acc[mt][nt][r] + bias;
        }
    }
}

// ---------------------------------------------------------------------------
extern "C" void kernel_launch(void* const* d_in, const int* in_sizes, int n_in,
                              void* d_out, int out_size, void* d_ws, size_t ws_size,
                              hipStream_t stream)
{
    const float* x   = (const float*)d_in[0];
    const float* dk  = (const float*)d_in[1];
    const float* dv  = (const float*)d_in[2];
    const float* Wq  = (const float*)d_in[3];
    const float* bq  = (const float*)d_in[4];
    const float* Wkv = (const float*)d_in[5];
    const float* bkv = (const float*)d_in[6];
    const float* Wp  = (const float*)d_in[7];
    const float* bpj = (const float*)d_in[8];

    float* out = (float*)d_out;
    float* ok  = out + 6291456;            // k output (8,1024,2,64)
    float* ov  = out + 7340032;            // v output

    char* ws = (char*)d_ws;
    short* q_ws  = (short*)(ws);                    // 12,582,912 B
    short* k_ws  = (short*)(ws + 12582912);         //  4,194,304 B (frag layout)
    short* vT_ws = (short*)(ws + 16777216);         //  4,194,304 B (frag layout)
    short* o_ws  = (short*)(ws + 20971520);         // 12,582,912 B  (32 MiB total)

    prep_k     <<<dim3(2048), 256, 0, stream>>>(x, Wq, bq, Wkv, bkv, dk, dv,
                                                ok, ov, q_ws, k_ws, vT_ws);
    attn_k     <<<dim3(768),  256, 0, stream>>>(q_ws, k_ws, vT_ws, o_ws);
    projgemm_k <<<dim3(768),  256, 0, stream>>>(o_ws, Wp, bpj, out);
}

// Round 5
// 211.366 us; speedup vs baseline: 1.0078x; 1.0078x over previous
//
#include <hip/hip_runtime.h>

using sh8 = __attribute__((ext_vector_type(8))) short;
using sh4 = __attribute__((ext_vector_type(4))) short;
using fx4 = __attribute__((ext_vector_type(4))) float;

#define MFMA(a,b,c)   __builtin_amdgcn_mfma_f32_16x16x32_bf16((a),(b),(c),0,0,0)

// RNE cast (epilogue scalars — accuracy-critical path)
__device__ __forceinline__ short f2bf(float f) {
    union { float f; unsigned u; } v; v.f = f;
    return (short)((v.u + 0x7fffu + ((v.u >> 16) & 1u)) >> 16);
}

// Single-instruction RNE pack of two floats to a bf16 pair (lo in low half).
__device__ __forceinline__ unsigned cvtpk(float lo, float hi) {
    unsigned r;
    asm("v_cvt_pk_bf16_f32 %0, %1, %2" : "=v"(r) : "v"(lo), "v"(hi));
    return r;
}

__device__ __forceinline__ sh8 pack8(float4 a, float4 b) {
    union { unsigned u[4]; sh8 s; } r;
    r.u[0] = cvtpk(a.x, a.y);
    r.u[1] = cvtpk(a.z, a.w);
    r.u[2] = cvtpk(b.x, b.y);
    r.u[3] = cvtpk(b.z, b.w);
    return r.s;
}

// q scale: D^-0.5 * log2(e) folded together; attn uses exp2 directly.
#define QSCALE 0.18033688011112042f

// DMA one 1KB chunk: per-lane global src, wave-uniform LDS dst (+lane*16 by HW)
#define GLOAD_LDS16(gsrc, ldst) __builtin_amdgcn_global_load_lds( \
    (const __attribute__((address_space(1))) void*)(gsrc),        \
    (__attribute__((address_space(3))) void*)(ldst), 16, 0, 0)

// ===========================================================================
// cast_k: one-shot fp32->bf16 of x (8192x768), Wq (768x768), Wkv (256x768)
// into the out-buffer's main region (dead until projgemm_k).  Removes all
// pack VALU + halves staged bytes in prep's GEMM hot loop.
// ===========================================================================
__global__ __launch_bounds__(256) void cast_k(const float* __restrict__ x,
                                              const float* __restrict__ Wq,
                                              const float* __restrict__ Wkv,
                                              short* __restrict__ xbf,
                                              short* __restrict__ wqbf,
                                              short* __restrict__ wkvbf)
{
    const int blk = blockIdx.x, t = threadIdx.x;
    const float* src; short* dst; size_t idx8;
    if (blk < 3072)      { src = x;   dst = xbf;   idx8 = ((size_t)blk * 256 + t) * 8; }
    else if (blk < 3360) { src = Wq;  dst = wqbf;  idx8 = ((size_t)(blk - 3072) * 256 + t) * 8; }
    else                 { src = Wkv; dst = wkvbf; idx8 = ((size_t)(blk - 3360) * 256 + t) * 8; }
    float4 a = *(const float4*)(src + idx8);
    float4 b = *(const float4*)(src + idx8 + 4);
    *(sh8*)&dst[idx8] = pack8(a, b);
}

// ===========================================================================
// Fragment layouts (written by prep_k, consumed by attn_k):
//   k_ws : per bh, 256 chunks of 512 shorts. chunk fo = (kb*4+nt)*2+half
//          holds K[key=kb*64+nt*16+llo][d=half*32+lhi*8+j] at lane=lhi*16+llo,
//          slot j.  Group (kb,g) -> 4 consecutive chunks at fo = (kb*2+g)*4.
//   vT_ws: per bh, 256 chunks of 512 shorts. chunk vo = (kb*2+g)*4+dt holds
//          V[key=kb*64+g*32+(i>>2)*16+lhi*4+(i&3)][d=dt*16+llo] at
//          lane=lhi*16+llo, slot i.
//   Chunks are lane-linear (lane*16B) => global_load_lds-compatible.
// ===========================================================================

// prep_k: merged qgemm+kvgemm (blocks 0..511, XCD-co-resident swizzle) +
// depth_k cast (512..1535) + depth_v fragment gather (1536..2047).
// GEMM staging now reads pre-cast bf16 (no pack VALU in the hot loop).
__global__ __launch_bounds__(256) void prep_k(const short* __restrict__ xbf,
                                              const short* __restrict__ wqbf,
                                              const short* __restrict__ wkvbf,
                                              const float* __restrict__ bq,
                                              const float* __restrict__ bkv,
                                              const float* __restrict__ dk,
                                              const float* __restrict__ dv,
                                              float* __restrict__ ok,
                                              float* __restrict__ ov,
                                              short* __restrict__ q_ws,
                                              short* __restrict__ k_ws,
                                              short* __restrict__ vT_ws)
{
    __shared__ alignas(16) short Al[128 * 40];
    __shared__ alignas(16) short Bl[128 * 40];
    const int blk = blockIdx.x;
    const int t   = threadIdx.x;

    if (blk < 512) {
        // ----- 128x128-tile bf16 GEMM path (qgemm or kvgemm) -----
        // XCD x8 = blk&7 owns m-tiles [8*x8, 8*x8+8); 8 n-tiles co-resident.
        const int x8 = blk & 7, jj = blk >> 3;       // jj in [0,64)
        const int m  = x8 * 8 + (jj >> 3);           // [0,64)
        const int nn = jj & 7;                       // 0..5 q, 6..7 kv
        const bool isq = (nn < 6);
        const int  bm  = m * 128, bn = (isq ? nn : nn - 6) * 128;
        const short* Wmat = isq ? wqbf : wkvbf;

        const int wave = t >> 6, lane = t & 63;
        const int wm   = wave >> 1, wn = wave & 1;
        const int lhi  = lane >> 4, llo = lane & 15;

        const int srow = t >> 1, scol = (t & 1) * 16;
        const short* ap = xbf  + (size_t)(bm + srow) * 768 + scol;
        const short* bp = Wmat + (size_t)(bn + srow) * 768 + scol;

        fx4 zero = {0.f, 0.f, 0.f, 0.f};
        fx4 acc[4][4];
        #pragma unroll
        for (int a = 0; a < 4; ++a)
            #pragma unroll
            for (int b2 = 0; b2 < 4; ++b2) acc[a][b2] = zero;

        sh8 qa0 = *(const sh8*)(ap), qa1 = *(const sh8*)(ap + 8);
        sh8 qb0 = *(const sh8*)(bp), qb1 = *(const sh8*)(bp + 8);

        for (int k0 = 0; k0 < 768; k0 += 32) {
            __syncthreads();
            *(sh8*)&Al[srow*40 + scol]     = qa0;
            *(sh8*)&Al[srow*40 + scol + 8] = qa1;
            *(sh8*)&Bl[srow*40 + scol]     = qb0;
            *(sh8*)&Bl[srow*40 + scol + 8] = qb1;
            __syncthreads();
            if (k0 + 32 < 768) {
                qa0 = *(const sh8*)(ap + k0+32);  qa1 = *(const sh8*)(ap + k0+40);
                qb0 = *(const sh8*)(bp + k0+32);  qb1 = *(const sh8*)(bp + k0+40);
            }
            sh8 af[4], bf[4];
            #pragma unroll
            for (int mt = 0; mt < 4; ++mt)
                af[mt] = *(const sh8*)&Al[(wm*64 + mt*16 + llo)*40 + lhi*8];
            #pragma unroll
            for (int nt = 0; nt < 4; ++nt)
                bf[nt] = *(const sh8*)&Bl[(wn*64 + nt*16 + llo)*40 + lhi*8];
            #pragma unroll
            for (int mt = 0; mt < 4; ++mt)
                #pragma unroll
                for (int nt = 0; nt < 4; ++nt)
                    acc[mt][nt] = MFMA(af[mt], bf[nt], acc[mt][nt]);
        }

        if (isq) {
            #pragma unroll
            for (int nt = 0; nt < 4; ++nt) {
                const int c = bn + wn*64 + nt*16 + llo;
                const float bias = bq[c];
                const int g = c >> 7, h = (c >> 6) & 1, d = c & 63;
                #pragma unroll
                for (int mt = 0; mt < 4; ++mt) {
                    const int m0 = bm + wm*64 + mt*16 + lhi*4;
                    #pragma unroll
                    for (int r = 0; r < 4; ++r) {
                        const int mr = m0 + r;
                        const int b = mr >> 10, n = mr & 1023;
                        const float val = (acc[mt][nt][r] + bias) * QSCALE;
                        q_ws[((size_t)(b*2 + h)*6144 + n*6 + g)*64 + d] = f2bf(val);
                    }
                }
            }
        } else {
            #pragma unroll
            for (int nt = 0; nt < 4; ++nt) {
                const int c = bn + wn*64 + nt*16 + llo;     // 0..255
                const float bias = bkv[c];
                const int s = c >> 7, h = (c >> 6) & 1, d = c & 63;
                #pragma unroll
                for (int mt = 0; mt < 4; ++mt) {
                    const int m0 = bm + wm*64 + mt*16 + lhi*4;
                    const int b = m0 >> 10, n0 = m0 & 1023;
                    float vals[4];
                    #pragma unroll
                    for (int r = 0; r < 4; ++r) vals[r] = acc[mt][nt][r] + bias;
                    const int key = 1024 + n0;              // n0 % 4 == 0
                    if (s == 0) {
                        #pragma unroll
                        for (int r = 0; r < 4; ++r)
                            ok[((size_t)(b*1024 + n0 + r)*2 + h)*64 + d] = vals[r];
                        const int kb_ = key >> 6, nt_ = (key >> 4) & 3;
                        const int half = d >> 5, lhiK = (d >> 3) & 3, jK = d & 7;
                        const size_t base = (size_t)(b*2 + h)*131072
                            + (size_t)(((((kb_*4 + nt_)*2 + half)*64) + lhiK*16 + (key & 15))*8 + jK);
                        #pragma unroll
                        for (int r = 0; r < 4; ++r)
                            k_ws[base + r*8] = f2bf(vals[r]);
                    } else {
                        #pragma unroll
                        for (int r = 0; r < 4; ++r)
                            ov[((size_t)(b*1024 + n0 + r)*2 + h)*64 + d] = vals[r];
                        const int kb_ = key >> 6, g_ = (key >> 5) & 1, k5 = key & 31;
                        const int half5 = k5 >> 4, lhi5 = (k5 >> 2) & 3;   // j5 = r
                        const int dt_ = d >> 4, llov = d & 15;
                        short4 pk = make_short4(f2bf(vals[0]), f2bf(vals[1]),
                                                f2bf(vals[2]), f2bf(vals[3]));
                        const size_t base = (size_t)(b*2 + h)*131072
                            + (size_t)(((((kb_*2 + g_)*4 + dt_)*64) + lhi5*16 + llov)*8 + half5*4);
                        *(short4*)&vT_ws[base] = pk;
                    }
                }
            }
        }
    } else if (blk < 1536) {
        // ----- depth_k cast: [b][tt][h][d] fp32 -> k_ws fragment layout -----
        const size_t idx4 = ((size_t)(blk - 512) * 256 + t) * 4;
        const int b  = (int)(idx4 >> 17);
        const int rm = (int)(idx4 & 131071);
        const int tt = rm >> 7, h = (rm >> 6) & 1, d = rm & 63;   // d % 4 == 0
        float4 v = *(const float4*)(dk + idx4);
        short4 pk = make_short4(f2bf(v.x), f2bf(v.y), f2bf(v.z), f2bf(v.w));
        const int kb_ = tt >> 6, nt_ = (tt >> 4) & 3, lloK = tt & 15;
        const int half = d >> 5, lhiK = (d >> 3) & 3, jK = d & 7;  // jK in {0,4}
        const size_t addr = (size_t)(b*2 + h)*131072
            + (size_t)(((((kb_*4 + nt_)*2 + half)*64) + lhiK*16 + lloK)*8 + jK);
        *(short4*)&k_ws[addr] = pk;
    } else {
        // ----- depth_v: direct gather into V fragment layout -----
        const int unit = (blk - 1536)*4 + (t >> 6);   // 0..2047
        const int lane = t & 63, lhi = lane >> 4, llo = lane & 15;
        const int dt_ = unit & 3, g_ = (unit >> 2) & 1;
        const int kb_ = (unit >> 3) & 15, bh = unit >> 7;
        const int b = bh >> 1, h = bh & 1;
        const float* s0 = dv
            + ((size_t)((b*1024 + kb_*64 + g_*32 + lhi*4)*2 + h))*64 + dt_*16 + llo;
        union { short s[8]; sh8 v8; } o;
        #pragma unroll
        for (int jv = 0; jv < 4; ++jv) o.s[jv]     = f2bf(s0[(size_t)jv * 128]);
        #pragma unroll
        for (int jv = 0; jv < 4; ++jv) o.s[4 + jv] = f2bf(s0[(size_t)(16 + jv) * 128]);
        *(sh8*)&vT_ws[((size_t)bh*256 + (kb_*2 + g_)*4 + dt_)*512 + lane*8] = o.v8;
    }
}

// ---------------------------------------------------------------------------
// Attention v10 = R3's proven schedule (ring-4, 32-key groups, counted
// vmcnt(4) — loads stay in flight across barriers) + R4's bh-co-location
// swizzle (XCD x8 owns bh {2*x8, 2*x8+1}; K/V 1 MB lives in that XCD's L2 —
// measured FETCH 39 MB -> 10 MB).
// ---------------------------------------------------------------------------
__global__ __launch_bounds__(256) void attn_k(const short* __restrict__ q_ws,
                                              const short* __restrict__ k_ws,
                                              const short* __restrict__ vT_ws,
                                              short* __restrict__ o_ws)
{
    __shared__ alignas(16) short L[4][8][512];   // ring buf: 4 x (4 K + 4 V chunks)
    const int t    = threadIdx.x;
    const int wave = t >> 6, lane = t & 63;
    const int lhi  = lane >> 4, llo = lane & 15;
    const int blk  = blockIdx.x;
    const int x8   = blk & 7, jj = blk >> 3;       // jj in [0,96)
    const int bh   = x8 * 2 + (jj >= 48 ? 1 : 0);
    const int qt   = (jj >= 48) ? (jj - 48) : jj;  // [0,48)
    const int b    = bh >> 1, h = bh & 1;

    const short* qb = q_ws + ((size_t)bh*6144 + qt*128 + wave*32) * 64;
    sh8 qf[2][2];
    #pragma unroll
    for (int s = 0; s < 2; ++s) {
        qf[s][0] = *(const sh8*)(qb + (s*16 + llo)*64 + lhi*8);
        qf[s][1] = *(const sh8*)(qb + (s*16 + llo)*64 + lhi*8 + 32);
    }

    const short* kbase = k_ws  + (size_t)bh*131072;
    const short* vbase = vT_ws + (size_t)bh*131072;

    fx4 zero = {0.f, 0.f, 0.f, 0.f};
    fx4 oacc[2][4];
    fx4 lacc[2];
    #pragma unroll
    for (int s = 0; s < 2; ++s) {
        lacc[s] = zero;
        #pragma unroll
        for (int dt = 0; dt < 4; ++dt) oacc[s][dt] = zero;
    }

    union { unsigned u[4]; sh8 s8; } onesu;
    onesu.u[0] = onesu.u[1] = onesu.u[2] = onesu.u[3] = 0x3F803F80u;  // bf16 1.0 x8
    const sh8 ones = onesu.s8;

    // wave w DMAs K-chunk w and V-chunk w of group g into ring slot g&3.
    auto stage = [&](int g) {
        const short* ks = kbase + ((size_t)g*4 + wave)*512 + lane*8;
        const short* vs = vbase + ((size_t)g*4 + wave)*512 + lane*8;
        GLOAD_LDS16(ks, &L[g & 3][wave][0]);
        GLOAD_LDS16(vs, &L[g & 3][4 + wave][0]);
    };

    stage(0);
    stage(1);                     // outstanding: 4 DMA ops per wave

    for (int g = 0; g < 64; ++g) {
        if (g < 62) {
            stage(g + 2);         // outstanding 6
            asm volatile("s_waitcnt vmcnt(4)" ::: "memory");   // group g landed
        } else if (g == 62) {
            asm volatile("s_waitcnt vmcnt(2)" ::: "memory");
        } else {
            asm volatile("s_waitcnt vmcnt(0)" ::: "memory");
        }
        __builtin_amdgcn_s_barrier();          // all waves' group-g DMAs visible
        __builtin_amdgcn_sched_barrier(0);     // forbid hoisting ds_reads above

        const short* Lb = (const short*)&L[g & 3][0][0];
        const int lo = lane * 8;
        sh8 K0 = *(const sh8*)(Lb + lo);
        sh8 K1 = *(const sh8*)(Lb + 512  + lo);
        sh8 K2 = *(const sh8*)(Lb + 1024 + lo);
        sh8 K3 = *(const sh8*)(Lb + 1536 + lo);
        sh8 V0 = *(const sh8*)(Lb + 2048 + lo);
        sh8 V1 = *(const sh8*)(Lb + 2560 + lo);
        sh8 V2 = *(const sh8*)(Lb + 3072 + lo);
        sh8 V3 = *(const sh8*)(Lb + 3584 + lo);

        #pragma unroll
        for (int s = 0; s < 2; ++s) {
            fx4 stA = MFMA(K0, qf[s][0], zero); stA = MFMA(K1, qf[s][1], stA);
            fx4 stB = MFMA(K2, qf[s][0], zero); stB = MFMA(K3, qf[s][1], stB);
            float pa0 = __builtin_amdgcn_exp2f(stA[0]);
            float pa1 = __builtin_amdgcn_exp2f(stA[1]);
            float pa2 = __builtin_amdgcn_exp2f(stA[2]);
            float pa3 = __builtin_amdgcn_exp2f(stA[3]);
            float pb0 = __builtin_amdgcn_exp2f(stB[0]);
            float pb1 = __builtin_amdgcn_exp2f(stB[1]);
            float pb2 = __builtin_amdgcn_exp2f(stB[2]);
            float pb3 = __builtin_amdgcn_exp2f(stB[3]);
            union { unsigned u[4]; sh8 s8; } pu;
            pu.u[0] = cvtpk(pa0, pa1);
            pu.u[1] = cvtpk(pa2, pa3);
            pu.u[2] = cvtpk(pb0, pb1);
            pu.u[3] = cvtpk(pb2, pb3);
            lacc[s]    = MFMA(pu.s8, ones, lacc[s]);
            oacc[s][0] = MFMA(pu.s8, V0, oacc[s][0]);
            oacc[s][1] = MFMA(pu.s8, V1, oacc[s][1]);
            oacc[s][2] = MFMA(pu.s8, V2, oacc[s][2]);
            oacc[s][3] = MFMA(pu.s8, V3, oacc[s][3]);
        }
    }

    // epilogue: lacc[s][r] already holds the full denominator for q-row
    // s*16 + lhi*4 + r (identical across llo) — no shuffles needed.
    #pragma unroll
    for (int s = 0; s < 2; ++s) {
        #pragma unroll
        for (int r = 0; r < 4; ++r) {
            const float iq = 1.0f / lacc[s][r];
            const int qi = qt*128 + wave*32 + s*16 + lhi*4 + r;
            const int n = qi / 6, g = qi % 6;
            short* orow = o_ws + ((size_t)(b*1024 + n))*768 + g*128 + h*64;
            #pragma unroll
            for (int dt = 0; dt < 4; ++dt)
                orow[dt*16 + llo] = f2bf(oacc[s][dt][r] * iq);
        }
    }
}

// ---------------------------------------------------------------------------
// proj GEMM: out = o(8192x768,bf16) @ Wproj^T + bproj -> fp32.
// 128x64 tiles, 768 blocks = 3/CU balanced, XCD-co-residency swizzle.
// ---------------------------------------------------------------------------
__global__ __launch_bounds__(256) void projgemm_k(const short* __restrict__ o_ws,
                                                  const float* __restrict__ Wp,
                                                  const float* __restrict__ bpj,
                                                  float* __restrict__ out)
{
    __shared__ alignas(16) short Al[128 * 40];
    __shared__ alignas(16) short Bl[64 * 40];
    const int t    = threadIdx.x;
    const int wave = t >> 6, lane = t & 63;
    const int wm   = wave >> 1, wn = wave & 1;
    const int lhi  = lane >> 4, llo = lane & 15;
    const int x8   = blockIdx.x & 7, jj = blockIdx.x >> 3;   // jj in [0,96)
    const int bm   = (x8*8 + jj/12) * 128;
    const int bn   = (jj % 12) * 64;

    const int srow = t >> 1, scol = (t & 1) * 16;       // A stage: 128 rows x 32
    const int brow = t >> 2, bcol = (t & 3) * 8;        // B stage: 64 rows x 32
    const short* ap = o_ws + (size_t)(bm + srow) * 768 + scol;
    const float* bp = Wp   + (size_t)(bn + brow) * 768 + bcol;

    fx4 zero = {0.f, 0.f, 0.f, 0.f};
    fx4 acc[4][2];
    #pragma unroll
    for (int i = 0; i < 4; ++i)
        #pragma unroll
        for (int j2 = 0; j2 < 2; ++j2) acc[i][j2] = zero;

    sh8 qa0 = *(const sh8*)(ap), qa1 = *(const sh8*)(ap + 8);
    float4 pb0 = *(const float4*)(bp), pb1 = *(const float4*)(bp + 4);

    for (int k0 = 0; k0 < 768; k0 += 32) {
        __syncthreads();
        *(sh8*)&Al[srow*40 + scol] = qa0;
        *(sh8*)&Al[srow*40 + scol + 8] = qa1;
        *(sh8*)&Bl[brow*40 + bcol] = pack8(pb0, pb1);
        __syncthreads();
        if (k0 + 32 < 768) {
            qa0 = *(const sh8*)(ap + k0+32);  qa1 = *(const sh8*)(ap + k0+40);
            pb0 = *(const float4*)(bp + k0+32);  pb1 = *(const float4*)(bp + k0+36);
        }
        sh8 af[4], bf[2];
        #pragma unroll
        for (int mt = 0; mt < 4; ++mt)
            af[mt] = *(const sh8*)&Al[(wm*64 + mt*16 + llo)*40 + lhi*8];
        #pragma unroll
        for (int nt = 0; nt < 2; ++nt)
            bf[nt] = *(const sh8*)&Bl[(wn*32 + nt*16 + llo)*40 + lhi*8];
        #pragma unroll
        for (int mt = 0; mt < 4; ++mt)
            #pragma unroll
            for (int nt = 0; nt < 2; ++nt)
                acc[mt][nt] = MFMA(af[mt], bf[nt], acc[mt][nt]);
    }

    #pragma unroll
    for (int nt = 0; nt < 2; ++nt) {
        const int c = bn + wn*32 + nt*16 + llo;
        const float bias = bpj[c];
        #pragma unroll
        for (int mt = 0; mt < 4; ++mt) {
            const int m0 = bm + wm*64 + mt*16 + lhi*4;
            #pragma unroll
            for (int r = 0; r < 4; ++r)
                out[(size_t)(m0 + r)*768 + c] = acc[mt][nt][r] + bias;
        }
    }
}

// ---------------------------------------------------------------------------
extern "C" void kernel_launch(void* const* d_in, const int* in_sizes, int n_in,
                              void* d_out, int out_size, void* d_ws, size_t ws_size,
                              hipStream_t stream)
{
    const float* x   = (const float*)d_in[0];
    const float* dk  = (const float*)d_in[1];
    const float* dv  = (const float*)d_in[2];
    const float* Wq  = (const float*)d_in[3];
    const float* bq  = (const float*)d_in[4];
    const float* Wkv = (const float*)d_in[5];
    const float* bkv = (const float*)d_in[6];
    const float* Wp  = (const float*)d_in[7];
    const float* bpj = (const float*)d_in[8];

    float* out = (float*)d_out;
    float* ok  = out + 6291456;            // k output (8,1024,2,64)
    float* ov  = out + 7340032;            // v output

    // bf16 scratch inside the out-buffer's main region (dead until projgemm):
    // xbf 12.6 MB + Wq_bf 1.2 MB + Wkv_bf 0.4 MB = 14.2 MB < 24 MB.
    short* xbf   = (short*)out;
    short* wqbf  = xbf + 6291456;
    short* wkvbf = wqbf + 589824;

    char* ws = (char*)d_ws;
    short* q_ws  = (short*)(ws);                    // 12,582,912 B
    short* k_ws  = (short*)(ws + 12582912);         //  4,194,304 B (frag layout)
    short* vT_ws = (short*)(ws + 16777216);         //  4,194,304 B (frag layout)
    short* o_ws  = (short*)(ws + 20971520);         // 12,582,912 B  (32 MiB total)

    cast_k     <<<dim3(3456), 256, 0, stream>>>(x, Wq, Wkv, xbf, wqbf, wkvbf);
    prep_k     <<<dim3(2048), 256, 0, stream>>>(xbf, wqbf, wkvbf, bq, bkv, dk, dv,
                                                ok, ov, q_ws, k_ws, vT_ws);
    attn_k     <<<dim3(768),  256, 0, stream>>>(q_ws, k_ws, vT_ws, o_ws);
    projgemm_k <<<dim3(768),  256, 0, stream>>>(o_ws, Wp, bpj, out);
}